// Round 4
// baseline (1907.874 us; speedup 1.0000x reference)
//
#include <hip/hip_runtime.h>
#include <math.h>

// ============================================================================
// StableHolographicLayer — round 4: wave-independent pipeline.
//
// Each wave owns 16 batch rows end-to-end. Lane l (g=l>>4, lr=l&15):
//   A-pattern (LN1 out, S, x): row lr, cols ks*32+g*8+i  (ks 0..3, i 0..7)
//     -> matches MFMA 16x16x32 A-fragment map directly: NO LDS for A.
//   D-pattern (MFMA out):      rows g*4+j, cols nt*16+lr (j 0..3)
// Two wave-private 8KB LDS repacks per module (GELU-out D->A, state D->A),
// ordered by the wave's in-order DS pipeline: no barriers for correctness.
// One __syncthreads() per module only to phase-align waves for L1 B-reuse.
// Precision: split-bf16 (hi+lo), 3 MFMAs (ah*bh, al*bh, ah*bl), fp32 acc;
// k-accumulation orders identical to rounds 1/3.
// LDS: 4 waves x 8KB = 32KB/block.
// ============================================================================

#define NMOD 8

typedef float  f32x4  __attribute__((ext_vector_type(4)));
typedef __bf16 bf16x8 __attribute__((ext_vector_type(8)));
typedef unsigned short u16x8 __attribute__((ext_vector_type(8)));

union U16B { u16x8 u; bf16x8 b; };

// workspace byte offsets
#define WS_W1 0u          // [8][2][4][16][64][8] u16 : 1 MiB
#define WS_W2 1048576u    // [8][2][8][8][64][8]  u16 : 1 MiB
#define WS_CW 2097152u    // [2][4][8][64][8]     u16 : 64 KiB
#define WS_FV 2162688u    // [8][128] f32 : 4 KiB

static __device__ __forceinline__ unsigned short f32_to_bf16_rn(float f) {
    union { float f; unsigned u; } a; a.f = f;
    unsigned u = a.u;
    u += 0x7fffu + ((u >> 16) & 1u);
    return (unsigned short)(u >> 16);
}
static __device__ __forceinline__ float bf16_to_f32(unsigned short h) {
    union { unsigned u; float f; } a; a.u = ((unsigned)h) << 16;
    return a.f;
}
static __device__ __forceinline__ float gelu_exact(float y) {
    return 0.5f * y * (1.0f + erff(y * 0.70710678118654752440f));
}

#define MFMA16(a, b, c) __builtin_amdgcn_mfma_f32_16x16x32_bf16((a), (b), (c), 0, 0, 0)

// ---------------------------------------------------------------------------
// Setup kernels (unchanged from rounds 1/3 — validated layouts).
// ---------------------------------------------------------------------------
__global__ void setup_weights(const float* __restrict__ w1,
                              const float* __restrict__ w2,
                              const float* __restrict__ cw,
                              unsigned short* __restrict__ w1cv,
                              unsigned short* __restrict__ w2cv,
                              unsigned short* __restrict__ cwcv)
{
    unsigned id = blockIdx.x * blockDim.x + threadIdx.x;
    if (id < 262144u) {                       // w1: [8][128][256]
        unsigned i8 = id & 7u;
        unsigned l  = (id >> 3) & 63u;
        unsigned nt = (id >> 9) & 15u;
        unsigned ks = (id >> 13) & 3u;
        unsigned mo = id >> 15;
        unsigned k = ks * 32u + ((l >> 4) << 3) + i8;
        unsigned c = nt * 16u + (l & 15u);
        float v = w1[(mo * 128u + k) * 256u + c];
        unsigned short hh = f32_to_bf16_rn(v);
        unsigned short ll = f32_to_bf16_rn(v - bf16_to_f32(hh));
        w1cv[((((mo * 2u + 0u) * 4u + ks) * 16u + nt) * 64u + l) * 8u + i8] = hh;
        w1cv[((((mo * 2u + 1u) * 4u + ks) * 16u + nt) * 64u + l) * 8u + i8] = ll;
    } else if (id < 524288u) {                // w2: [8][256][128]
        unsigned id2 = id - 262144u;
        unsigned i8 = id2 & 7u;
        unsigned l  = (id2 >> 3) & 63u;
        unsigned nt = (id2 >> 9) & 7u;
        unsigned kt = (id2 >> 12) & 7u;
        unsigned mo = id2 >> 15;
        unsigned k = kt * 32u + ((l >> 4) << 3) + i8;
        unsigned c = nt * 16u + (l & 15u);
        float v = w2[(mo * 256u + k) * 128u + c];
        unsigned short hh = f32_to_bf16_rn(v);
        unsigned short ll = f32_to_bf16_rn(v - bf16_to_f32(hh));
        w2cv[((((mo * 2u + 0u) * 8u + kt) * 8u + nt) * 64u + l) * 8u + i8] = hh;
        w2cv[((((mo * 2u + 1u) * 8u + kt) * 8u + nt) * 64u + l) * 8u + i8] = ll;
    } else if (id < 540672u) {                // comb_w: [128][128]
        unsigned id3 = id - 524288u;
        unsigned i8 = id3 & 7u;
        unsigned l  = (id3 >> 3) & 63u;
        unsigned nt = (id3 >> 9) & 7u;
        unsigned ks = id3 >> 12;
        unsigned k = ks * 32u + ((l >> 4) << 3) + i8;
        unsigned c = nt * 16u + (l & 15u);
        float v = cw[k * 128u + c];
        unsigned short hh = f32_to_bf16_rn(v);
        unsigned short ll = f32_to_bf16_rn(v - bf16_to_f32(hh));
        cwcv[(((0u * 4u + ks) * 8u + nt) * 64u + l) * 8u + i8] = hh;
        cwcv[(((1u * 4u + ks) * 8u + nt) * 64u + l) * 8u + i8] = ll;
    }
}

__global__ void setup_fv(const float* __restrict__ fb,
                         const float* __restrict__ sm,
                         float* __restrict__ fv)
{
    unsigned tid = blockIdx.x * blockDim.x + threadIdx.x;   // 0..1023
    unsigned i = tid >> 7, d = tid & 127u;
    float px = (float)((i >> 2) & 1u);
    float py = (float)((i >> 1) & 1u);
    float pz = (float)(i & 1u);
    float dot = px * sm[(i * 3u + 0u) * 128u + d]
              + py * sm[(i * 3u + 1u) * 128u + d]
              + pz * sm[(i * 3u + 2u) * 128u + d];
    float pw = 1.0f / (1.0f + expf(-dot));
    float mb = 0.0f;
    #pragma unroll
    for (int k = 0; k < 8; ++k) mb += fb[(i * 8u + (unsigned)k) * 128u + d];
    mb *= 0.125f;
    fv[i * 128u + d] = pw * mb;
}

// ---------------------------------------------------------------------------
// Main kernel. grid = 2048 x 256. 4 waves/block, 16 rows/wave, 32KB LDS.
// ---------------------------------------------------------------------------
__global__ __launch_bounds__(256, 2)
void holo_main(const float* __restrict__ x,
               const float* __restrict__ ln1_g, const float* __restrict__ ln1_b,
               const float* __restrict__ bias1, const float* __restrict__ bias2,
               const float* __restrict__ ln2_g, const float* __restrict__ ln2_b,
               const float* __restrict__ cln_g, const float* __restrict__ cln_b,
               const float* __restrict__ comb_b,
               const unsigned short* __restrict__ w1cv,
               const unsigned short* __restrict__ w2cv,
               const unsigned short* __restrict__ cwcv,
               const float* __restrict__ fv,
               float* __restrict__ out)
{
    __shared__ __align__(16) unsigned char lds[32768];

    const unsigned t  = threadIdx.x;
    const unsigned w  = t >> 6;
    const unsigned l  = t & 63u;
    const unsigned lr = l & 15u;       // A-pattern row; D-pattern col (within tile)
    const unsigned g  = l >> 4;        // lane group 0..3
    const unsigned R0 = blockIdx.x * 64u + w * 16u;   // wave's first batch row
    const unsigned sR = (lr >> 2) & 3u;               // read-side swizzle key

    unsigned char* ldsw = lds + w * 8192u;  // wave-private 8KB

    const f32x4 FZ = {0.f, 0.f, 0.f, 0.f};

    float Sv[32];                       // A-pattern: [ks][i]
    #pragma unroll
    for (int j = 0; j < 32; ++j) Sv[j] = 0.f;

    for (int mod = 0; mod < NMOD; ++mod) {
        const unsigned mo = (unsigned)mod;
        // ---------------- LN1 (A-pattern, registers) ----------------
        bf16x8 ah[4], al[4];
        {
            const float coef = (mod == 0) ? 0.0f : (0.1f / (float)mod);
            float h[32];
            #pragma unroll
            for (int ks = 0; ks < 4; ++ks) {
                const float* xb  = x  + (R0 + lr) * 128u + (unsigned)ks * 32u + g * 8u;
                const float* fb_ = fv + mo * 128u + (unsigned)ks * 32u + g * 8u;
                float4 x0 = *(const float4*)xb, x1 = *(const float4*)(xb + 4);
                float4 f0 = *(const float4*)fb_, f1 = *(const float4*)(fb_ + 4);
                h[ks*8+0] = x0.x + f0.x + coef * Sv[ks*8+0];
                h[ks*8+1] = x0.y + f0.y + coef * Sv[ks*8+1];
                h[ks*8+2] = x0.z + f0.z + coef * Sv[ks*8+2];
                h[ks*8+3] = x0.w + f0.w + coef * Sv[ks*8+3];
                h[ks*8+4] = x1.x + f1.x + coef * Sv[ks*8+4];
                h[ks*8+5] = x1.y + f1.y + coef * Sv[ks*8+5];
                h[ks*8+6] = x1.z + f1.z + coef * Sv[ks*8+6];
                h[ks*8+7] = x1.w + f1.w + coef * Sv[ks*8+7];
            }
            float s = 0.f, ss = 0.f;
            #pragma unroll
            for (int j = 0; j < 32; ++j) { s += h[j]; ss += h[j] * h[j]; }
            s += __shfl_xor(s, 16); ss += __shfl_xor(ss, 16);
            s += __shfl_xor(s, 32); ss += __shfl_xor(ss, 32);
            const float mean = s * (1.0f / 128.0f);
            const float var  = ss * (1.0f / 128.0f) - mean * mean;
            const float rstd = 1.0f / sqrtf(var + 1e-5f);
            #pragma unroll
            for (int ks = 0; ks < 4; ++ks) {
                const float* gb = ln1_g + mo * 128u + (unsigned)ks * 32u + g * 8u;
                const float* bb = ln1_b + mo * 128u + (unsigned)ks * 32u + g * 8u;
                float4 g0 = *(const float4*)gb, g1 = *(const float4*)(gb + 4);
                float4 b0 = *(const float4*)bb, b1 = *(const float4*)(bb + 4);
                float gg[8] = {g0.x,g0.y,g0.z,g0.w,g1.x,g1.y,g1.z,g1.w};
                float bv[8] = {b0.x,b0.y,b0.z,b0.w,b1.x,b1.y,b1.z,b1.w};
                U16B vh, vl;
                #pragma unroll
                for (int e = 0; e < 8; ++e) {
                    float nv = (h[ks*8+e] - mean) * rstd * gg[e] + bv[e];
                    unsigned short hh = f32_to_bf16_rn(nv);
                    vh.u[e] = hh;
                    vl.u[e] = f32_to_bf16_rn(nv - bf16_to_f32(hh));
                }
                ah[ks] = vh.b; al[ks] = vl.b;
            }
        }
        __syncthreads();   // phase alignment only (L1 B-fragment reuse)

        f32x4 acc2[8];
        #pragma unroll
        for (int n = 0; n < 8; ++n) acc2[n] = FZ;

        #pragma unroll
        for (int hh2 = 0; hh2 < 2; ++hh2) {
            // ---- GEMM1 half: A(regs) @ w1[:, hh2*128..+128) ----
            f32x4 acc1[8];
            #pragma unroll
            for (int n = 0; n < 8; ++n) acc1[n] = FZ;
            #pragma unroll
            for (int nt = 0; nt < 8; ++nt) {
                unsigned ntg = (unsigned)hh2 * 8u + (unsigned)nt;
                bf16x8 bh[4], bl[4];
                #pragma unroll
                for (int ks = 0; ks < 4; ++ks) {
                    bh[ks] = *(const bf16x8*)(const void*)
                        (w1cv + (((mo * 2u + 0u) * 4u + (unsigned)ks) * 16u + ntg) * 512u + l * 8u);
                    bl[ks] = *(const bf16x8*)(const void*)
                        (w1cv + (((mo * 2u + 1u) * 4u + (unsigned)ks) * 16u + ntg) * 512u + l * 8u);
                }
                #pragma unroll
                for (int ks = 0; ks < 4; ++ks) {
                    acc1[nt] = MFMA16(ah[ks], bh[ks], acc1[nt]);
                    acc1[nt] = MFMA16(al[ks], bh[ks], acc1[nt]);
                    acc1[nt] = MFMA16(ah[ks], bl[ks], acc1[nt]);
                }
            }
            // ---- bias1 + GELU -> H planes (wave-private, D-pattern write) ----
            #pragma unroll
            for (int nt = 0; nt < 8; ++nt) {
                unsigned colg = ((unsigned)hh2 * 8u + (unsigned)nt) * 16u + lr;
                float bb = bias1[mo * 256u + colg];
                #pragma unroll
                for (int j = 0; j < 4; ++j) {
                    float ge = gelu_exact(acc1[nt][j] + bb);
                    unsigned short hi = f32_to_bf16_rn(ge);
                    unsigned short lo = f32_to_bf16_rn(ge - bf16_to_f32(hi));
                    unsigned rho = g * 4u + (unsigned)j;
                    unsigned byteH = ((rho * 256u + ((unsigned)nt * 16u + lr) * 2u) ^ (g << 5));
                    *(unsigned short*)(ldsw + byteH)         = hi;
                    *(unsigned short*)(ldsw + 4096u + byteH) = lo;
                }
            }
            // ---- read back A'-fragments (A-pattern) ----
            bf16x8 a2h[4], a2l[4];
            #pragma unroll
            for (int kt = 0; kt < 4; ++kt) {
                unsigned byteR = ((lr * 256u + (unsigned)kt * 64u + g * 16u) ^ (sR << 5));
                a2h[kt] = *(const bf16x8*)(ldsw + byteR);
                a2l[kt] = *(const bf16x8*)(ldsw + 4096u + byteR);
            }
            // ---- GEMM2 partial: H @ w2[hh2*128..+128, :] ----
            #pragma unroll
            for (int nt = 0; nt < 8; ++nt) {
                bf16x8 b2h[4], b2l[4];
                #pragma unroll
                for (int kt = 0; kt < 4; ++kt) {
                    unsigned ktg = (unsigned)hh2 * 4u + (unsigned)kt;
                    b2h[kt] = *(const bf16x8*)(const void*)
                        (w2cv + (((mo * 2u + 0u) * 8u + ktg) * 8u + (unsigned)nt) * 512u + l * 8u);
                    b2l[kt] = *(const bf16x8*)(const void*)
                        (w2cv + (((mo * 2u + 1u) * 8u + ktg) * 8u + (unsigned)nt) * 512u + l * 8u);
                }
                #pragma unroll
                for (int kt = 0; kt < 4; ++kt) {
                    acc2[nt] = MFMA16(a2h[kt], b2h[kt], acc2[nt]);
                    acc2[nt] = MFMA16(a2l[kt], b2h[kt], acc2[nt]);
                    acc2[nt] = MFMA16(a2h[kt], b2l[kt], acc2[nt]);
                }
            }
        }
        // ---------------- bias2 + LN2 (D-pattern) ----------------
        {
            float o[8][4];
            #pragma unroll
            for (int nt = 0; nt < 8; ++nt) {
                float bb = bias2[mo * 128u + (unsigned)nt * 16u + lr];
                #pragma unroll
                for (int j = 0; j < 4; ++j) o[nt][j] = acc2[nt][j] + bb;
            }
            float mean[4], rstd[4];
            #pragma unroll
            for (int j = 0; j < 4; ++j) {
                float s = 0.f, ss = 0.f;
                #pragma unroll
                for (int nt = 0; nt < 8; ++nt) { s += o[nt][j]; ss += o[nt][j] * o[nt][j]; }
                s += __shfl_xor(s, 1); ss += __shfl_xor(ss, 1);
                s += __shfl_xor(s, 2); ss += __shfl_xor(ss, 2);
                s += __shfl_xor(s, 4); ss += __shfl_xor(ss, 4);
                s += __shfl_xor(s, 8); ss += __shfl_xor(ss, 8);
                mean[j] = s * (1.0f / 128.0f);
                float var = ss * (1.0f / 128.0f) - mean[j] * mean[j];
                rstd[j] = 1.0f / sqrtf(var + 1e-5f);
            }
            // state (D-pattern) -> wave-private f32 buffer
            #pragma unroll
            for (int nt = 0; nt < 8; ++nt) {
                unsigned col = (unsigned)nt * 16u + lr;
                float g2 = ln2_g[mo * 128u + col];
                float b2v = ln2_b[mo * 128u + col];
                #pragma unroll
                for (int j = 0; j < 4; ++j) {
                    float nv = (o[nt][j] - mean[j]) * rstd[j] * g2 + b2v;
                    unsigned rho = g * 4u + (unsigned)j;
                    unsigned byteS = ((rho * 512u + col * 4u) ^ (g << 5));
                    *(float*)(ldsw + byteS) = nv;
                }
            }
            // read back A-pattern, accumulate S
            #pragma unroll
            for (int ks = 0; ks < 4; ++ks) {
                unsigned byteR = ((lr * 512u + (unsigned)ks * 128u + g * 32u) ^ (sR << 5));
                float4 v0 = *(const float4*)(ldsw + byteR);
                float4 v1 = *(const float4*)(ldsw + (byteR ^ 16u));
                // note: +16 within a 32B-aligned base; XOR-swizzle bits are 5..6 so ^16 == +16
                Sv[ks*8+0] += v0.x; Sv[ks*8+1] += v0.y; Sv[ks*8+2] += v0.z; Sv[ks*8+3] += v0.w;
                Sv[ks*8+4] += v1.x; Sv[ks*8+5] += v1.y; Sv[ks*8+6] += v1.z; Sv[ks*8+7] += v1.w;
            }
        }
    }

    // ---------------- final: LN(S/8) -> A-frags ----------------
    bf16x8 ah[4], al[4];
    {
        float h[32];
        #pragma unroll
        for (int j = 0; j < 32; ++j) h[j] = Sv[j] * 0.125f;
        float s = 0.f, ss = 0.f;
        #pragma unroll
        for (int j = 0; j < 32; ++j) { s += h[j]; ss += h[j] * h[j]; }
        s += __shfl_xor(s, 16); ss += __shfl_xor(ss, 16);
        s += __shfl_xor(s, 32); ss += __shfl_xor(ss, 32);
        const float mean = s * (1.0f / 128.0f);
        const float var  = ss * (1.0f / 128.0f) - mean * mean;
        const float rstd = 1.0f / sqrtf(var + 1e-5f);
        #pragma unroll
        for (int ks = 0; ks < 4; ++ks) {
            const float* gb = cln_g + (unsigned)ks * 32u + g * 8u;
            const float* bb = cln_b + (unsigned)ks * 32u + g * 8u;
            float4 g0 = *(const float4*)gb, g1 = *(const float4*)(gb + 4);
            float4 b0 = *(const float4*)bb, b1 = *(const float4*)(bb + 4);
            float gg[8] = {g0.x,g0.y,g0.z,g0.w,g1.x,g1.y,g1.z,g1.w};
            float bv[8] = {b0.x,b0.y,b0.z,b0.w,b1.x,b1.y,b1.z,b1.w};
            U16B vh, vl;
            #pragma unroll
            for (int e = 0; e < 8; ++e) {
                float nv = (h[ks*8+e] - mean) * rstd * gg[e] + bv[e];
                unsigned short hh2 = f32_to_bf16_rn(nv);
                vh.u[e] = hh2;
                vl.u[e] = f32_to_bf16_rn(nv - bf16_to_f32(hh2));
            }
            ah[ks] = vh.b; al[ks] = vl.b;
        }
    }
    // ---------------- final GEMM + store (D-pattern) ----------------
    {
        f32x4 acc3[8];
        #pragma unroll
        for (int n = 0; n < 8; ++n) acc3[n] = FZ;
        #pragma unroll
        for (int nt = 0; nt < 8; ++nt) {
            bf16x8 bh[4], bl[4];
            #pragma unroll
            for (int ks = 0; ks < 4; ++ks) {
                bh[ks] = *(const bf16x8*)(const void*)
                    (cwcv + ((0u * 4u + (unsigned)ks) * 8u + (unsigned)nt) * 512u + l * 8u);
                bl[ks] = *(const bf16x8*)(const void*)
                    (cwcv + ((1u * 4u + (unsigned)ks) * 8u + (unsigned)nt) * 512u + l * 8u);
            }
            #pragma unroll
            for (int ks = 0; ks < 4; ++ks) {
                acc3[nt] = MFMA16(ah[ks], bh[ks], acc3[nt]);
                acc3[nt] = MFMA16(al[ks], bh[ks], acc3[nt]);
                acc3[nt] = MFMA16(ah[ks], bl[ks], acc3[nt]);
            }
        }
        #pragma unroll
        for (int nt = 0; nt < 8; ++nt) {
            unsigned col = (unsigned)nt * 16u + lr;
            float bb = comb_b[col];
            #pragma unroll
            for (int j = 0; j < 4; ++j) {
                out[(R0 + g * 4u + (unsigned)j) * 128u + col] = acc3[nt][j] + bb;
            }
        }
    }
}

extern "C" void kernel_launch(void* const* d_in, const int* in_sizes, int n_in,
                              void* d_out, int out_size, void* d_ws, size_t ws_size,
                              hipStream_t stream)
{
    const float* x    = (const float*)d_in[0];
    const float* fb   = (const float*)d_in[1];
    const float* sm   = (const float*)d_in[2];
    const float* ln1g = (const float*)d_in[3];
    const float* ln1b = (const float*)d_in[4];
    const float* w1   = (const float*)d_in[5];
    const float* b1   = (const float*)d_in[6];
    const float* w2   = (const float*)d_in[7];
    const float* b2   = (const float*)d_in[8];
    const float* ln2g = (const float*)d_in[9];
    const float* ln2b = (const float*)d_in[10];
    const float* clng = (const float*)d_in[11];
    const float* clnb = (const float*)d_in[12];
    const float* cw   = (const float*)d_in[13];
    const float* cb   = (const float*)d_in[14];
    float* out = (float*)d_out;
    char* ws = (char*)d_ws;
    unsigned short* w1cv = (unsigned short*)(ws + WS_W1);
    unsigned short* w2cv = (unsigned short*)(ws + WS_W2);
    unsigned short* cwcv = (unsigned short*)(ws + WS_CW);
    float*          fvp  = (float*)(ws + WS_FV);

    setup_weights<<<dim3(2112), dim3(256), 0, stream>>>(w1, w2, cw, w1cv, w2cv, cwcv);
    setup_fv<<<dim3(4), dim3(256), 0, stream>>>(fb, sm, fvp);
    holo_main<<<dim3(2048), dim3(256), 0, stream>>>(x, ln1g, ln1b, b1, b2, ln2g, ln2b,
                                                    clng, clnb, cb, w1cv, w2cv, cwcv, fvp, out);
    (void)in_sizes; (void)n_in; (void)out_size; (void)ws_size;
}

// Round 5
// 850.082 us; speedup vs baseline: 2.2443x; 2.2443x over previous
//
#include <hip/hip_runtime.h>
#include <math.h>

// ============================================================================
// StableHolographicLayer — round 5: round-1 dataflow at 32 rows/block.
//
// Math per mod i: h = x + fv[i] + (i? 0.1/i*S : 0); h=LN1(h);
//   g=GELU(h@w1+b1); o=g@w2+b2; S += LN2(o).  out = LN(S/8)@comb_w + comb_b.
// Precision: split-bf16 (hi+lo) MFMA 16x16x32, 3 products, fp32 acc.
// Same barrier topology / k-order / column-split as round 1 (948us champion);
// changes: 32-row blocks (LDS 32KB -> 4 blocks/CU, 16 waves/CU),
// native __bf16 RNE casts (less VALU), x reloaded per module (fewer VGPR).
// ============================================================================

#define NMOD 8

typedef float  f32x4  __attribute__((ext_vector_type(4)));
typedef __bf16 bf16x8 __attribute__((ext_vector_type(8)));

// LDS byte offsets (total 32 KB)
#define AHI_OFF 0u        // [32][128] bf16 hi, swizzled  (8 KB)
#define ALO_OFF 8192u     // [32][128] bf16 lo            (8 KB)
#define HHI_OFF 16384u    // [32][128] bf16 hi (half)     (8 KB)
#define HLO_OFF 24576u    // [32][128] bf16 lo (half)     (8 KB)
// f32 [32][128] state buffer reuses bytes 0..16383.

// workspace byte offsets
#define WS_W1 0u          // [8][2][4][16][64][8] u16 : 1 MiB
#define WS_W2 1048576u    // [8][2][8][8][64][8]  u16 : 1 MiB
#define WS_CW 2097152u    // [2][4][8][64][8]     u16 : 64 KiB
#define WS_FV 2162688u    // [8][128] f32 : 4 KiB

static __device__ __forceinline__ unsigned short f32_to_bf16_rn(float f) {
    union { float f; unsigned u; } a; a.f = f;
    unsigned u = a.u;
    u += 0x7fffu + ((u >> 16) & 1u);
    return (unsigned short)(u >> 16);
}
static __device__ __forceinline__ float bf16_to_f32(unsigned short h) {
    union { unsigned u; float f; } a; a.u = ((unsigned)h) << 16;
    return a.f;
}
static __device__ __forceinline__ float gelu_exact(float y) {
    return 0.5f * y * (1.0f + erff(y * 0.70710678118654752440f));
}

#define MFMA16(a, b, c) __builtin_amdgcn_mfma_f32_16x16x32_bf16((a), (b), (c), 0, 0, 0)

// ---------------------------------------------------------------------------
// Setup kernels (unchanged — validated layouts).
// ---------------------------------------------------------------------------
__global__ void setup_weights(const float* __restrict__ w1,
                              const float* __restrict__ w2,
                              const float* __restrict__ cw,
                              unsigned short* __restrict__ w1cv,
                              unsigned short* __restrict__ w2cv,
                              unsigned short* __restrict__ cwcv)
{
    unsigned id = blockIdx.x * blockDim.x + threadIdx.x;
    if (id < 262144u) {                       // w1: [8][128][256]
        unsigned i8 = id & 7u;
        unsigned l  = (id >> 3) & 63u;
        unsigned nt = (id >> 9) & 15u;
        unsigned ks = (id >> 13) & 3u;
        unsigned mo = id >> 15;
        unsigned k = ks * 32u + ((l >> 4) << 3) + i8;
        unsigned c = nt * 16u + (l & 15u);
        float v = w1[(mo * 128u + k) * 256u + c];
        unsigned short hh = f32_to_bf16_rn(v);
        unsigned short ll = f32_to_bf16_rn(v - bf16_to_f32(hh));
        w1cv[((((mo * 2u + 0u) * 4u + ks) * 16u + nt) * 64u + l) * 8u + i8] = hh;
        w1cv[((((mo * 2u + 1u) * 4u + ks) * 16u + nt) * 64u + l) * 8u + i8] = ll;
    } else if (id < 524288u) {                // w2: [8][256][128]
        unsigned id2 = id - 262144u;
        unsigned i8 = id2 & 7u;
        unsigned l  = (id2 >> 3) & 63u;
        unsigned nt = (id2 >> 9) & 7u;
        unsigned kt = (id2 >> 12) & 7u;
        unsigned mo = id2 >> 15;
        unsigned k = kt * 32u + ((l >> 4) << 3) + i8;
        unsigned c = nt * 16u + (l & 15u);
        float v = w2[(mo * 256u + k) * 128u + c];
        unsigned short hh = f32_to_bf16_rn(v);
        unsigned short ll = f32_to_bf16_rn(v - bf16_to_f32(hh));
        w2cv[((((mo * 2u + 0u) * 8u + kt) * 8u + nt) * 64u + l) * 8u + i8] = hh;
        w2cv[((((mo * 2u + 1u) * 8u + kt) * 8u + nt) * 64u + l) * 8u + i8] = ll;
    } else if (id < 540672u) {                // comb_w: [128][128]
        unsigned id3 = id - 524288u;
        unsigned i8 = id3 & 7u;
        unsigned l  = (id3 >> 3) & 63u;
        unsigned nt = (id3 >> 9) & 7u;
        unsigned ks = id3 >> 12;
        unsigned k = ks * 32u + ((l >> 4) << 3) + i8;
        unsigned c = nt * 16u + (l & 15u);
        float v = cw[k * 128u + c];
        unsigned short hh = f32_to_bf16_rn(v);
        unsigned short ll = f32_to_bf16_rn(v - bf16_to_f32(hh));
        cwcv[(((0u * 4u + ks) * 8u + nt) * 64u + l) * 8u + i8] = hh;
        cwcv[(((1u * 4u + ks) * 8u + nt) * 64u + l) * 8u + i8] = ll;
    }
}

__global__ void setup_fv(const float* __restrict__ fb,
                         const float* __restrict__ sm,
                         float* __restrict__ fv)
{
    unsigned tid = blockIdx.x * blockDim.x + threadIdx.x;   // 0..1023
    unsigned i = tid >> 7, d = tid & 127u;
    float px = (float)((i >> 2) & 1u);
    float py = (float)((i >> 1) & 1u);
    float pz = (float)(i & 1u);
    float dot = px * sm[(i * 3u + 0u) * 128u + d]
              + py * sm[(i * 3u + 1u) * 128u + d]
              + pz * sm[(i * 3u + 2u) * 128u + d];
    float pw = 1.0f / (1.0f + expf(-dot));
    float mb = 0.0f;
    #pragma unroll
    for (int k = 0; k < 8; ++k) mb += fb[(i * 8u + (unsigned)k) * 128u + d];
    mb *= 0.125f;
    fv[i * 128u + d] = pw * mb;
}

// ---------------------------------------------------------------------------
// Main kernel. grid = 4096 x 256, 32 rows/block, 32 KB LDS, 4 blocks/CU.
// ---------------------------------------------------------------------------
__global__ __launch_bounds__(256, 4)
void holo_main(const float* __restrict__ x,
               const float* __restrict__ ln1_g, const float* __restrict__ ln1_b,
               const float* __restrict__ bias1, const float* __restrict__ bias2,
               const float* __restrict__ ln2_g, const float* __restrict__ ln2_b,
               const float* __restrict__ cln_g, const float* __restrict__ cln_b,
               const float* __restrict__ comb_b,
               const unsigned short* __restrict__ w1cv,
               const unsigned short* __restrict__ w2cv,
               const unsigned short* __restrict__ cwcv,
               const float* __restrict__ fv,
               float* __restrict__ out)
{
    __shared__ __align__(16) unsigned char lds[32768];

    const unsigned t  = threadIdx.x;
    const unsigned r  = t >> 3;        // LN-phase row 0..31
    const unsigned q8 = t & 7u;        // LN-phase col group (16 cols)
    const unsigned w  = t >> 6;        // wave 0..3
    const unsigned l  = t & 63u;       // lane
    const unsigned lr = l & 15u;
    const unsigned lg = l >> 4;
    const unsigned drow = lg * 4u;     // D-fragment base row
    const unsigned row0 = blockIdx.x * 32u;

    const f32x4 FZ = {0.f, 0.f, 0.f, 0.f};

    float Sv[16];
    #pragma unroll
    for (int j = 0; j < 16; ++j) Sv[j] = 0.f;

    for (int mod = 0; mod < NMOD; ++mod) {
        const unsigned mo = (unsigned)mod;
        // ------------- LN1(x + fv + coef*S) -> A planes (bf16 hi/lo) -------------
        {
            const float coef = (mod == 0) ? 0.0f : (0.1f / (float)mod);
            float h[16];
            const float4* xp  = (const float4*)(x  + (row0 + r) * 128u + q8 * 16u);
            const float4* fvp = (const float4*)(fv + mo * 128u + q8 * 16u);
            #pragma unroll
            for (int u = 0; u < 4; ++u) {
                float4 xv = xp[u];
                float4 f4 = fvp[u];
                h[4*u+0] = xv.x + f4.x + coef * Sv[4*u+0];
                h[4*u+1] = xv.y + f4.y + coef * Sv[4*u+1];
                h[4*u+2] = xv.z + f4.z + coef * Sv[4*u+2];
                h[4*u+3] = xv.w + f4.w + coef * Sv[4*u+3];
            }
            float s = 0.f, ss = 0.f;
            #pragma unroll
            for (int j = 0; j < 16; ++j) { s += h[j]; ss += h[j] * h[j]; }
            s += __shfl_xor(s, 1); ss += __shfl_xor(ss, 1);
            s += __shfl_xor(s, 2); ss += __shfl_xor(ss, 2);
            s += __shfl_xor(s, 4); ss += __shfl_xor(ss, 4);
            const float mean = s * (1.0f / 128.0f);
            const float var  = ss * (1.0f / 128.0f) - mean * mean;
            const float rstd = 1.0f / sqrtf(var + 1e-5f);
            const float4* gp = (const float4*)(ln1_g + mo * 128u + q8 * 16u);
            const float4* bp = (const float4*)(ln1_b + mo * 128u + q8 * 16u);
            float gg[16], bv[16];
            #pragma unroll
            for (int u = 0; u < 4; ++u) {
                float4 g4 = gp[u], b4 = bp[u];
                gg[4*u+0]=g4.x; gg[4*u+1]=g4.y; gg[4*u+2]=g4.z; gg[4*u+3]=g4.w;
                bv[4*u+0]=b4.x; bv[4*u+1]=b4.y; bv[4*u+2]=b4.z; bv[4*u+3]=b4.w;
            }
            #pragma unroll
            for (int e2 = 0; e2 < 2; ++e2) {
                bf16x8 vh, vl;
                #pragma unroll
                for (int e = 0; e < 8; ++e) {
                    float nv = (h[e2*8+e] - mean) * rstd * gg[e2*8+e] + bv[e2*8+e];
                    __bf16 hb = (__bf16)nv;
                    vh[e] = hb;
                    vl[e] = (__bf16)(nv - (float)hb);
                }
                unsigned off = ((r * 256u + q8 * 32u + (unsigned)e2 * 16u) ^ ((r & 7u) << 4));
                *(bf16x8*)(lds + AHI_OFF + off) = vh;
                *(bf16x8*)(lds + ALO_OFF + off) = vl;
            }
        }
        __syncthreads();

        f32x4 acc2[2][2];
        #pragma unroll
        for (int m = 0; m < 2; ++m) { acc2[m][0] = FZ; acc2[m][1] = FZ; }

        #pragma unroll
        for (int hN = 0; hN < 2; ++hN) {
            // ---- GEMM1 half hN: A[32x128] @ w1[:, hN*128..+128) ----
            f32x4 acc1[2][2];
            #pragma unroll
            for (int m = 0; m < 2; ++m) { acc1[m][0] = FZ; acc1[m][1] = FZ; }
            #pragma unroll
            for (int ks = 0; ks < 4; ++ks) {
                bf16x8 ah[2], al[2];
                #pragma unroll
                for (int m = 0; m < 2; ++m) {
                    unsigned rowA = (unsigned)m * 16u + lr;
                    unsigned off = ((rowA * 256u + (unsigned)ks * 64u + lg * 16u) ^ ((lr & 7u) << 4));
                    ah[m] = *(const bf16x8*)(lds + AHI_OFF + off);
                    al[m] = *(const bf16x8*)(lds + ALO_OFF + off);
                }
                #pragma unroll
                for (int n = 0; n < 2; ++n) {
                    unsigned ntg = (unsigned)hN * 8u + w * 2u + (unsigned)n;
                    const bf16x8 bh = *(const bf16x8*)(const void*)
                        (w1cv + (((mo * 2u + 0u) * 4u + (unsigned)ks) * 16u + ntg) * 512u + l * 8u);
                    const bf16x8 bl = *(const bf16x8*)(const void*)
                        (w1cv + (((mo * 2u + 1u) * 4u + (unsigned)ks) * 16u + ntg) * 512u + l * 8u);
                    #pragma unroll
                    for (int m = 0; m < 2; ++m) {
                        acc1[m][n] = MFMA16(ah[m], bh, acc1[m][n]);
                        acc1[m][n] = MFMA16(al[m], bh, acc1[m][n]);
                        acc1[m][n] = MFMA16(ah[m], bl, acc1[m][n]);
                    }
                }
            }
            if (hN == 1) __syncthreads();   // all waves done reading H(0) & A
            // ---- bias1 + exact GELU -> H planes ----
            #pragma unroll
            for (int n = 0; n < 2; ++n) {
                unsigned c128 = w * 32u + (unsigned)n * 16u + lr;
                float bb = bias1[mo * 256u + (unsigned)hN * 128u + c128];
                #pragma unroll
                for (int m = 0; m < 2; ++m) {
                    #pragma unroll
                    for (int j = 0; j < 4; ++j) {
                        unsigned rowA = (unsigned)m * 16u + drow + (unsigned)j;
                        float ge = gelu_exact(acc1[m][n][j] + bb);
                        __bf16 hb = (__bf16)ge;
                        __bf16 lb = (__bf16)(ge - (float)hb);
                        unsigned off = ((rowA * 256u + c128 * 2u) ^ ((rowA & 7u) << 4));
                        *(__bf16*)(lds + HHI_OFF + off) = hb;
                        *(__bf16*)(lds + HLO_OFF + off) = lb;
                    }
                }
            }
            __syncthreads();   // H(hN) ready
            // ---- GEMM2 pass hN: H[32x128] @ w2[hN*128..+128, :] -> acc2 ----
            #pragma unroll
            for (int ks = 0; ks < 4; ++ks) {
                unsigned kt = (unsigned)hN * 4u + (unsigned)ks;
                bf16x8 ah2[2], al2[2];
                #pragma unroll
                for (int m = 0; m < 2; ++m) {
                    unsigned rowA = (unsigned)m * 16u + lr;
                    unsigned off = ((rowA * 256u + (unsigned)ks * 64u + lg * 16u) ^ ((lr & 7u) << 4));
                    ah2[m] = *(const bf16x8*)(lds + HHI_OFF + off);
                    al2[m] = *(const bf16x8*)(lds + HLO_OFF + off);
                }
                #pragma unroll
                for (int n = 0; n < 2; ++n) {
                    unsigned nt2 = w * 2u + (unsigned)n;
                    const bf16x8 bh = *(const bf16x8*)(const void*)
                        (w2cv + (((mo * 2u + 0u) * 8u + kt) * 8u + nt2) * 512u + l * 8u);
                    const bf16x8 bl = *(const bf16x8*)(const void*)
                        (w2cv + (((mo * 2u + 1u) * 8u + kt) * 8u + nt2) * 512u + l * 8u);
                    #pragma unroll
                    for (int m = 0; m < 2; ++m) {
                        acc2[m][n] = MFMA16(ah2[m], bh, acc2[m][n]);
                        acc2[m][n] = MFMA16(al2[m], bh, acc2[m][n]);
                        acc2[m][n] = MFMA16(ah2[m], bl, acc2[m][n]);
                    }
                }
            }
        }
        // ---- acc2 + b2 -> f32 state buffer (reuses A region) ----
        #pragma unroll
        for (int n = 0; n < 2; ++n) {
            unsigned c = w * 32u + (unsigned)n * 16u + lr;
            float bb = bias2[mo * 128u + c];
            #pragma unroll
            for (int m = 0; m < 2; ++m) {
                #pragma unroll
                for (int j = 0; j < 4; ++j) {
                    unsigned rowA = (unsigned)m * 16u + drow + (unsigned)j;
                    unsigned off = ((rowA * 512u + c * 4u) ^ ((rowA & 7u) << 4));
                    *(float*)(lds + off) = acc2[m][n][j] + bb;
                }
            }
        }
        __syncthreads();
        // ------------- LN2 -> S += state -------------
        {
            float h2[16];
            #pragma unroll
            for (int e = 0; e < 4; ++e) {
                unsigned off = ((r * 512u + q8 * 64u + (unsigned)e * 16u) ^ ((r & 7u) << 4));
                float4 v = *(const float4*)(lds + off);
                h2[4*e+0] = v.x; h2[4*e+1] = v.y; h2[4*e+2] = v.z; h2[4*e+3] = v.w;
            }
            float s = 0.f, ss = 0.f;
            #pragma unroll
            for (int j = 0; j < 16; ++j) { s += h2[j]; ss += h2[j] * h2[j]; }
            s += __shfl_xor(s, 1); ss += __shfl_xor(ss, 1);
            s += __shfl_xor(s, 2); ss += __shfl_xor(ss, 2);
            s += __shfl_xor(s, 4); ss += __shfl_xor(ss, 4);
            const float mean = s * (1.0f / 128.0f);
            const float var  = ss * (1.0f / 128.0f) - mean * mean;
            const float rstd = 1.0f / sqrtf(var + 1e-5f);
            const float4* gp = (const float4*)(ln2_g + mo * 128u + q8 * 16u);
            const float4* bp = (const float4*)(ln2_b + mo * 128u + q8 * 16u);
            #pragma unroll
            for (int u = 0; u < 4; ++u) {
                float4 g4 = gp[u], b4 = bp[u];
                Sv[4*u+0] += (h2[4*u+0] - mean) * rstd * g4.x + b4.x;
                Sv[4*u+1] += (h2[4*u+1] - mean) * rstd * g4.y + b4.y;
                Sv[4*u+2] += (h2[4*u+2] - mean) * rstd * g4.z + b4.z;
                Sv[4*u+3] += (h2[4*u+3] - mean) * rstd * g4.w + b4.w;
            }
        }
        __syncthreads();   // A/state region rewritten next iteration
    }

    // ------------- final: LN(S/8) -> A planes -------------
    {
        float h[16];
        #pragma unroll
        for (int j = 0; j < 16; ++j) h[j] = Sv[j] * 0.125f;
        float s = 0.f, ss = 0.f;
        #pragma unroll
        for (int j = 0; j < 16; ++j) { s += h[j]; ss += h[j] * h[j]; }
        s += __shfl_xor(s, 1); ss += __shfl_xor(ss, 1);
        s += __shfl_xor(s, 2); ss += __shfl_xor(ss, 2);
        s += __shfl_xor(s, 4); ss += __shfl_xor(ss, 4);
        const float mean = s * (1.0f / 128.0f);
        const float var  = ss * (1.0f / 128.0f) - mean * mean;
        const float rstd = 1.0f / sqrtf(var + 1e-5f);
        const float4* gp = (const float4*)(cln_g + q8 * 16u);
        const float4* bp = (const float4*)(cln_b + q8 * 16u);
        float gg[16], bv[16];
        #pragma unroll
        for (int u = 0; u < 4; ++u) {
            float4 g4 = gp[u], b4 = bp[u];
            gg[4*u+0]=g4.x; gg[4*u+1]=g4.y; gg[4*u+2]=g4.z; gg[4*u+3]=g4.w;
            bv[4*u+0]=b4.x; bv[4*u+1]=b4.y; bv[4*u+2]=b4.z; bv[4*u+3]=b4.w;
        }
        #pragma unroll
        for (int e2 = 0; e2 < 2; ++e2) {
            bf16x8 vh, vl;
            #pragma unroll
            for (int e = 0; e < 8; ++e) {
                float nv = (h[e2*8+e] - mean) * rstd * gg[e2*8+e] + bv[e2*8+e];
                __bf16 hb = (__bf16)nv;
                vh[e] = hb;
                vl[e] = (__bf16)(nv - (float)hb);
            }
            unsigned off = ((r * 256u + q8 * 32u + (unsigned)e2 * 16u) ^ ((r & 7u) << 4));
            *(bf16x8*)(lds + AHI_OFF + off) = vh;
            *(bf16x8*)(lds + ALO_OFF + off) = vl;
        }
    }
    __syncthreads();
    // ------------- final GEMM: LN(s) @ comb_w + comb_b -> out -------------
    {
        f32x4 acc3[2][2];
        #pragma unroll
        for (int m = 0; m < 2; ++m) { acc3[m][0] = FZ; acc3[m][1] = FZ; }
        #pragma unroll
        for (int ks = 0; ks < 4; ++ks) {
            bf16x8 ah[2], al[2];
            #pragma unroll
            for (int m = 0; m < 2; ++m) {
                unsigned rowA = (unsigned)m * 16u + lr;
                unsigned off = ((rowA * 256u + (unsigned)ks * 64u + lg * 16u) ^ ((lr & 7u) << 4));
                ah[m] = *(const bf16x8*)(lds + AHI_OFF + off);
                al[m] = *(const bf16x8*)(lds + ALO_OFF + off);
            }
            #pragma unroll
            for (int n = 0; n < 2; ++n) {
                unsigned nt = w * 2u + (unsigned)n;
                const bf16x8 bh = *(const bf16x8*)(const void*)
                    (cwcv + ((0u * 4u + (unsigned)ks) * 8u + nt) * 512u + l * 8u);
                const bf16x8 bl = *(const bf16x8*)(const void*)
                    (cwcv + ((1u * 4u + (unsigned)ks) * 8u + nt) * 512u + l * 8u);
                #pragma unroll
                for (int m = 0; m < 2; ++m) {
                    acc3[m][n] = MFMA16(ah[m], bh, acc3[m][n]);
                    acc3[m][n] = MFMA16(al[m], bh, acc3[m][n]);
                    acc3[m][n] = MFMA16(ah[m], bl, acc3[m][n]);
                }
            }
        }
        #pragma unroll
        for (int n = 0; n < 2; ++n) {
            unsigned col = w * 32u + (unsigned)n * 16u + lr;
            float bb = comb_b[col];
            #pragma unroll
            for (int m = 0; m < 2; ++m) {
                #pragma unroll
                for (int j = 0; j < 4; ++j) {
                    unsigned rowA = (unsigned)m * 16u + drow + (unsigned)j;
                    out[(row0 + rowA) * 128u + col] = acc3[m][n][j] + bb;
                }
            }
        }
    }
}

extern "C" void kernel_launch(void* const* d_in, const int* in_sizes, int n_in,
                              void* d_out, int out_size, void* d_ws, size_t ws_size,
                              hipStream_t stream)
{
    const float* x    = (const float*)d_in[0];
    const float* fb   = (const float*)d_in[1];
    const float* sm   = (const float*)d_in[2];
    const float* ln1g = (const float*)d_in[3];
    const float* ln1b = (const float*)d_in[4];
    const float* w1   = (const float*)d_in[5];
    const float* b1   = (const float*)d_in[6];
    const float* w2   = (const float*)d_in[7];
    const float* b2   = (const float*)d_in[8];
    const float* ln2g = (const float*)d_in[9];
    const float* ln2b = (const float*)d_in[10];
    const float* clng = (const float*)d_in[11];
    const float* clnb = (const float*)d_in[12];
    const float* cw   = (const float*)d_in[13];
    const float* cb   = (const float*)d_in[14];
    float* out = (float*)d_out;
    char* ws = (char*)d_ws;
    unsigned short* w1cv = (unsigned short*)(ws + WS_W1);
    unsigned short* w2cv = (unsigned short*)(ws + WS_W2);
    unsigned short* cwcv = (unsigned short*)(ws + WS_CW);
    float*          fvp  = (float*)(ws + WS_FV);

    setup_weights<<<dim3(2112), dim3(256), 0, stream>>>(w1, w2, cw, w1cv, w2cv, cwcv);
    setup_fv<<<dim3(4), dim3(256), 0, stream>>>(fb, sm, fvp);
    holo_main<<<dim3(4096), dim3(256), 0, stream>>>(x, ln1g, ln1b, b1, b2, ln2g, ln2b,
                                                    clng, clnb, cb, w1cv, w2cv, cwcv, fvp, out);
    (void)in_sizes; (void)n_in; (void)out_size; (void)ws_size;
}